// Round 4
// baseline (99.539 us; speedup 1.0000x reference)
//
#include <hip/hip_runtime.h>

#define BATCH 64
#define H 1024
#define W 1024
#define RPB 32                 // rows per block strip
#define STRIPS (H / RPB)       // 32
#define NT 256                 // threads per block (W/4)
#define NB 512                 // log-spaced m^2 bins per region
#define NREG 5                 // quadrants 0..3 + "no-bin" region 4
#define NHIST (NREG * NB)      // 2560
#define BIN_BASE 3776          // (118<<5): lower edge m^2 = 2^-9
#define BIN_SHIFT 18           // keep exponent + 5 mantissa bits
#define INVN (1.0f / (float)(H * W))

// 4-byte-aligned float4 for the overlapping (col-1) load
typedef float f4u __attribute__((ext_vector_type(4), aligned(4)));

// col==0 thread loaded at col (not col-1): shift components so pl = {x0,x0,x1,x2}
// -> gx of pixel 0 becomes 0 (zero-pad of first column), others correct.
__device__ __forceinline__ f4u fix_col0(f4u p, int col) {
    if (col == 0) { p.w = p.z; p.z = p.y; p.y = p.x; }
    return p;
}

// One row of 4 pixels. FIRST = image row 0 (gy forced 0; angle==pi -> region 4).
template<bool FIRST>
__device__ __forceinline__ void do_row(const float4 cur, const float4 pv4, const f4u pl4,
                                       float& mx2, unsigned int* shHist) {
    float px[4] = {cur.x, cur.y, cur.z, cur.w};
    float pl[4] = {pl4.x, pl4.y, pl4.z, pl4.w};
    float pv[4] = {pv4.x, pv4.y, pv4.z, pv4.w};
    #pragma unroll
    for (int j = 0; j < 4; ++j) {
        float gx = px[j] - pl[j];
        float gy = FIRST ? 0.0f : (px[j] - pv[j]);
        float m2 = __builtin_fmaf(gx, gx, __builtin_fmaf(gy, gy, 1e-8f));
        mx2 = fmaxf(mx2, m2);
        // quadrant from sign bits of gy and gxp = gx + 1e-8:
        //  (sy,sxp)=(1,1)->q0 [-pi,-pi/2) ; (1,0)->q1 [-pi/2,0)
        //  (0,0)->q2 [0,pi/2)            ; (0,1)->q3 [pi/2,pi)
        //  row 0 (gy==0): gxp>=0 -> angle 0 (q2); gxp<0 -> angle pi -> NO bin (q4)
        unsigned int sxp = __float_as_uint(gx + 1e-8f) >> 31;
        unsigned int q;
        if (FIRST) {
            q = sxp ? 4u : 2u;
        } else {
            unsigned int sy = __float_as_uint(gy) >> 31;
            q = ((sy ^ 1u) << 1) | (sxp ^ sy);
        }
        // log-spaced bin straight from the float bits of m2 (m2 > 0 always)
        int bin = (int)(__float_as_uint(m2) >> BIN_SHIFT) - BIN_BASE;
        bin = bin < 0 ? 0 : (bin > (NB - 1) ? (NB - 1) : bin);
        atomicAdd(&shHist[q * NB + bin], 1u);
    }
}

// ---------------- Pass 1: per-strip 5-region histogram + max(m^2) ----------------
__global__ __launch_bounds__(NT) void pass1_kernel(const float* __restrict__ x,
                                                   unsigned int* __restrict__ hist,
                                                   unsigned int* __restrict__ maxbits) {
    const int strip = blockIdx.x;
    const int b = blockIdx.y;
    const int tid = threadIdx.x;
    const int col = tid << 2;
    const int plcol = (col == 0) ? 0 : col - 1;
    const float* img = x + (size_t)b * H * W;
    const int r0 = strip * RPB;
    const int rend = r0 + RPB;

    __shared__ unsigned int shHist[NHIST];
    for (int i = tid; i < NHIST; i += NT) shHist[i] = 0u;
    __syncthreads();

    float mx2 = 0.f;
    float4 prev;
    int r_begin;

    if (r0 == 0) {
        // peel image row 0 (gy==0 path with the no-bin case)
        float4 cur0 = *(const float4*)(img + col);
        f4u pl0 = fix_col0(*(const f4u*)(img + plcol), col);
        do_row<true>(cur0, cur0, pl0, mx2, shHist);
        prev = cur0;
        r_begin = 1;
    } else {
        prev = *(const float4*)(img + (size_t)(r0 - 1) * W + col);
        r_begin = r0;
    }

    float4 cur_pf = *(const float4*)(img + (size_t)r_begin * W + col);
    f4u    pl_pf  = *(const f4u*)(img + (size_t)r_begin * W + plcol);

    for (int r = r_begin; r < rend; ++r) {
        float4 cur = cur_pf;
        f4u pl = fix_col0(pl_pf, col);
        if (r + 1 < rend) {                      // issue next-row loads before body
            cur_pf = *(const float4*)(img + (size_t)(r + 1) * W + col);
            pl_pf  = *(const f4u*)(img + (size_t)(r + 1) * W + plcol);
        }
        do_row<false>(cur, prev, pl, mx2, shHist);
        prev = cur;
    }

    // edge_max: wave-reduce max(m^2), one global atomicMax per wave (positive floats
    // -> uint bit pattern is order-preserving)
    #pragma unroll
    for (int o = 32; o > 0; o >>= 1)
        mx2 = fmaxf(mx2, __shfl_down(mx2, o, 64));
    if ((tid & 63) == 0)
        atomicMax(maxbits + b, __float_as_uint(mx2));

    __syncthreads();   // all shHist atomics complete
    unsigned int* gh = hist + (size_t)(b * STRIPS + strip) * NHIST;
    for (int i = tid; i < NHIST; i += NT) gh[i] = shHist[i];   // coalesced stores
}

// ---------------- Finalize: one block per image, coalesced strip-sum ----------------
__global__ __launch_bounds__(NT) void finalize_kernel(const unsigned int* __restrict__ hist,
                                                      const unsigned int* __restrict__ maxbits,
                                                      float* __restrict__ out) {
    const int b = blockIdx.x;
    const int tid = threadIdx.x;
    const int wv = tid >> 6, ln = tid & 63;
    __shared__ float shRed[4][9];
    __shared__ float shS[4];
    __shared__ float shMean;

    // sum the 32 per-strip histograms; thread owns bins {k*256+tid} (coalesced reads)
    unsigned int acc[10];
    #pragma unroll
    for (int k = 0; k < 10; ++k) acc[k] = 0u;
    const unsigned int* basep = hist + (size_t)b * STRIPS * NHIST;
    for (int s = 0; s < STRIPS; ++s) {
        const unsigned int* src = basep + (size_t)s * NHIST;
        #pragma unroll
        for (int k = 0; k < 10; ++k) acc[k] += src[k * NT + tid];
    }

    // bin centers in m-space: [sqrt(lo)+sqrt(hi)]/2
    float mc[10];
    #pragma unroll
    for (int k = 0; k < 10; ++k) {
        int i = (k * NT + tid) & (NB - 1);
        float lo = __uint_as_float((unsigned int)(i + BIN_BASE) << BIN_SHIFT);
        float hi = __uint_as_float((unsigned int)(i + BIN_BASE + 1) << BIN_SHIFT);
        mc[k] = 0.5f * (sqrtf(lo) + sqrtf(hi));
    }

    // total sum of magnitudes -> mean
    float sv = 0.f;
    #pragma unroll
    for (int k = 0; k < 10; ++k) sv += (float)acc[k] * mc[k];
    #pragma unroll
    for (int o = 32; o > 0; o >>= 1) sv += __shfl_down(sv, o, 64);
    if (ln == 0) shS[wv] = sv;
    __syncthreads();
    if (tid == 0) {
        float mean = (shS[0] + shS[1] + shS[2] + shS[3]) * INVN;
        shMean = mean;
        out[b * 7 + 1] = mean;                                  // edge_strength
        out[b * 7 + 2] = sqrtf(__uint_as_float(maxbits[b]));    // edge_max (exact)
    }
    __syncthreads();
    const float mean = shMean;

    // density threshold position within its bin (interpolate in m-space)
    float mean2 = mean * mean;
    int kb = (int)(__float_as_uint(mean2) >> BIN_SHIFT) - BIN_BASE;
    kb = kb < 0 ? 0 : (kb > NB - 1 ? NB - 1 : kb);
    float lok = sqrtf(__uint_as_float((unsigned int)(kb + BIN_BASE) << BIN_SHIFT));
    float hik = sqrtf(__uint_as_float((unsigned int)(kb + BIN_BASE + 1) << BIN_SHIFT));
    float frac = (mean - lok) / (hik - lok);
    frac = fminf(fmaxf(frac, 0.f), 1.f);

    // per-quadrant {sum m, count} + density count (all regions), static indices only
    float v[9];
    #pragma unroll
    for (int k = 0; k < 9; ++k) v[k] = 0.f;
    #pragma unroll
    for (int k = 0; k < 10; ++k) {
        int idx = k * NT + tid;
        int q = idx >> 9;            // region 0..4
        int i = idx & (NB - 1);
        float h = (float)acc[k];
        float hm = h * mc[k];
        v[0] += (q == 0) ? hm : 0.f;  v[4] += (q == 0) ? h : 0.f;
        v[1] += (q == 1) ? hm : 0.f;  v[5] += (q == 1) ? h : 0.f;
        v[2] += (q == 2) ? hm : 0.f;  v[6] += (q == 2) ? h : 0.f;
        v[3] += (q == 3) ? hm : 0.f;  v[7] += (q == 3) ? h : 0.f;
        v[8] += (i > kb) ? h : ((i == kb) ? h * (1.f - frac) : 0.f);
    }
    #pragma unroll
    for (int k = 0; k < 9; ++k) {
        #pragma unroll
        for (int o = 32; o > 0; o >>= 1) v[k] += __shfl_down(v[k], o, 64);
    }
    if (ln == 0) {
        #pragma unroll
        for (int k = 0; k < 9; ++k) shRed[wv][k] = v[k];
    }
    __syncthreads();
    if (tid == 0) {
        float t[9];
        #pragma unroll
        for (int k = 0; k < 9; ++k)
            t[k] = shRed[0][k] + shRed[1][k] + shRed[2][k] + shRed[3][k];
        out[b * 7 + 0] = t[8] * INVN;               // edge_density
        out[b * 7 + 3] = t[0] / (t[4] + 1e-8f);     // angle features
        out[b * 7 + 4] = t[1] / (t[5] + 1e-8f);
        out[b * 7 + 5] = t[2] / (t[6] + 1e-8f);
        out[b * 7 + 6] = t[3] / (t[7] + 1e-8f);
    }
}

extern "C" void kernel_launch(void* const* d_in, const int* in_sizes, int n_in,
                              void* d_out, int out_size, void* d_ws, size_t ws_size,
                              hipStream_t stream) {
    const float* x = (const float*)d_in[0];
    float* out = (float*)d_out;

    unsigned int* hist = (unsigned int*)d_ws;                       // 64*32*2560 u32 ~ 21 MB
    unsigned int* maxbits = hist + (size_t)BATCH * STRIPS * NHIST;  // 64 u32

    hipMemsetAsync(maxbits, 0, BATCH * sizeof(unsigned int), stream);

    dim3 grid(STRIPS, BATCH);
    pass1_kernel<<<grid, NT, 0, stream>>>(x, hist, maxbits);
    finalize_kernel<<<BATCH, NT, 0, stream>>>(hist, maxbits, out);
}

// Round 5
// 79.410 us; speedup vs baseline: 1.2535x; 1.2535x over previous
//
#include <hip/hip_runtime.h>

#define BATCH 64
#define H 1024
#define W 1024
#define RPB 64                 // rows per block strip
#define STRIPS (H / RPB)       // 16
#define NT 256                 // threads per block (W/4)
#define NB 512                 // log-spaced m^2 bins per region
#define NREG 5                 // quadrants 0..3 + "no-bin" region 4
#define NHIST (NREG * NB)      // 2560
#define BIN_BASE 3776          // (118<<5): lower edge m^2 = 2^-9
#define BIN_SHIFT 18           // keep exponent + 5 mantissa bits
#define INVN (1.0f / (float)(H * W))

// One row of 4 pixels. FIRST = image row 0 (gy forced 0; angle==pi -> region 4).
template<bool FIRST>
__device__ __forceinline__ void do_row(const float4 cur, const float4 pv4, float left,
                                       int col, float& mx2, unsigned int* shHist) {
    float px[4] = {cur.x, cur.y, cur.z, cur.w};
    float pl[4] = {left, cur.x, cur.y, cur.z};
    float pv[4] = {pv4.x, pv4.y, pv4.z, pv4.w};
    #pragma unroll
    for (int j = 0; j < 4; ++j) {
        float gx = px[j] - pl[j];
        if (j == 0) gx = (col == 0) ? 0.f : gx;     // zero-pad of first column
        float gy = FIRST ? 0.0f : (px[j] - pv[j]);
        float m2 = __builtin_fmaf(gx, gx, __builtin_fmaf(gy, gy, 1e-8f));
        mx2 = fmaxf(mx2, m2);
        // quadrant from sign bits of gy and gxp = gx + 1e-8:
        //  (sy,sxp)=(1,1)->q0 [-pi,-pi/2) ; (1,0)->q1 [-pi/2,0)
        //  (0,0)->q2 [0,pi/2)            ; (0,1)->q3 [pi/2,pi)
        //  row 0 (gy==0): gxp>=0 -> angle 0 (q2); gxp<0 -> angle pi -> NO bin (q4)
        unsigned int sxp = __float_as_uint(gx + 1e-8f) >> 31;
        unsigned int q;
        if (FIRST) {
            q = sxp ? 4u : 2u;
        } else {
            unsigned int sy = __float_as_uint(gy) >> 31;
            q = ((sy ^ 1u) << 1) | (sxp ^ sy);
        }
        // log-spaced bin straight from the float bits of m2 (m2 > 0 always)
        int bin = (int)(__float_as_uint(m2) >> BIN_SHIFT) - BIN_BASE;
        bin = bin < 0 ? 0 : (bin > (NB - 1) ? (NB - 1) : bin);
        atomicAdd(&shHist[q * NB + bin], 1u);
    }
}

// ---------------- Pass 1: per-strip 5-region histogram + max(m^2) ----------------
__global__ __launch_bounds__(NT) void pass1_kernel(const float* __restrict__ x,
                                                   unsigned int* __restrict__ hist,
                                                   unsigned int* __restrict__ maxbits) {
    const int strip = blockIdx.x;
    const int b = blockIdx.y;
    const int tid = threadIdx.x;
    const int wave = tid >> 6;
    const int lane = tid & 63;
    const int seg0 = wave << 8;           // wave's 256-col segment base
    const int col = seg0 + (lane << 2);
    const float* img = x + (size_t)b * H * W;
    const int r0 = strip * RPB;
    const int rend = r0 + RPB;

    __shared__ unsigned int shHist[NHIST];
    for (int i = tid; i < NHIST; i += NT) shHist[i] = 0u;
    __syncthreads();

    float mx2 = 0.f;
    float4 prev;
    int r_begin;

    if (r0 == 0) {
        // peel image row 0 (gy==0 path with the no-bin case)
        float4 cur0 = *(const float4*)(img + col);
        float lb = 0.f;
        if (lane == 0 && seg0 > 0) lb = img[seg0 - 1];
        float sw = __shfl_up(cur0.w, 1, 64);
        float left = (lane == 0) ? lb : sw;
        do_row<true>(cur0, cur0, left, col, mx2, shHist);
        prev = cur0;
        r_begin = 1;
    } else {
        prev = *(const float4*)(img + (size_t)(r0 - 1) * W + col);
        r_begin = r0;
    }

    float4 cur_pf = *(const float4*)(img + (size_t)r_begin * W + col);

    for (int r = r_begin; r < rend; ++r) {
        float4 cur = cur_pf;
        if (r + 1 < rend)                       // prefetch next row before the body
            cur_pf = *(const float4*)(img + (size_t)(r + 1) * W + col);
        float lb = 0.f;
        if (lane == 0 && seg0 > 0) lb = img[(size_t)r * W + seg0 - 1];
        float sw = __shfl_up(cur.w, 1, 64);
        float left = (lane == 0) ? lb : sw;
        do_row<false>(cur, prev, left, col, mx2, shHist);
        prev = cur;
    }

    // edge_max: wave-reduce max(m^2), one global atomicMax per wave (positive floats
    // -> uint bit pattern is order-preserving)
    #pragma unroll
    for (int o = 32; o > 0; o >>= 1)
        mx2 = fmaxf(mx2, __shfl_down(mx2, o, 64));
    if (lane == 0)
        atomicMax(maxbits + b, __float_as_uint(mx2));

    __syncthreads();   // all shHist atomics complete
    unsigned int* gh = hist + (size_t)(b * STRIPS + strip) * NHIST;
    for (int i = tid; i < NHIST; i += NT) gh[i] = shHist[i];   // coalesced stores
}

// ---------------- Finalize: one block per image, coalesced strip-sum ----------------
__global__ __launch_bounds__(NT) void finalize_kernel(const unsigned int* __restrict__ hist,
                                                      const unsigned int* __restrict__ maxbits,
                                                      float* __restrict__ out) {
    const int b = blockIdx.x;
    const int tid = threadIdx.x;
    const int wv = tid >> 6, ln = tid & 63;
    __shared__ float shRed[4][9];
    __shared__ float shS[4];
    __shared__ float shMean;

    // sum the 16 per-strip histograms; thread owns bins {k*256+tid} (coalesced reads)
    unsigned int acc[10];
    #pragma unroll
    for (int k = 0; k < 10; ++k) acc[k] = 0u;
    const unsigned int* basep = hist + (size_t)b * STRIPS * NHIST;
    for (int s = 0; s < STRIPS; ++s) {
        const unsigned int* src = basep + (size_t)s * NHIST;
        #pragma unroll
        for (int k = 0; k < 10; ++k) acc[k] += src[k * NT + tid];
    }

    // bin centers in m-space: [sqrt(lo)+sqrt(hi)]/2
    float mc[10];
    #pragma unroll
    for (int k = 0; k < 10; ++k) {
        int i = (k * NT + tid) & (NB - 1);
        float lo = __uint_as_float((unsigned int)(i + BIN_BASE) << BIN_SHIFT);
        float hi = __uint_as_float((unsigned int)(i + BIN_BASE + 1) << BIN_SHIFT);
        mc[k] = 0.5f * (sqrtf(lo) + sqrtf(hi));
    }

    // total sum of magnitudes -> mean
    float sv = 0.f;
    #pragma unroll
    for (int k = 0; k < 10; ++k) sv += (float)acc[k] * mc[k];
    #pragma unroll
    for (int o = 32; o > 0; o >>= 1) sv += __shfl_down(sv, o, 64);
    if (ln == 0) shS[wv] = sv;
    __syncthreads();
    if (tid == 0) {
        float mean = (shS[0] + shS[1] + shS[2] + shS[3]) * INVN;
        shMean = mean;
        out[b * 7 + 1] = mean;                                  // edge_strength
        out[b * 7 + 2] = sqrtf(__uint_as_float(maxbits[b]));    // edge_max (exact)
    }
    __syncthreads();
    const float mean = shMean;

    // density threshold position within its bin (interpolate in m-space)
    float mean2 = mean * mean;
    int kb = (int)(__float_as_uint(mean2) >> BIN_SHIFT) - BIN_BASE;
    kb = kb < 0 ? 0 : (kb > NB - 1 ? NB - 1 : kb);
    float lok = sqrtf(__uint_as_float((unsigned int)(kb + BIN_BASE) << BIN_SHIFT));
    float hik = sqrtf(__uint_as_float((unsigned int)(kb + BIN_BASE + 1) << BIN_SHIFT));
    float frac = (mean - lok) / (hik - lok);
    frac = fminf(fmaxf(frac, 0.f), 1.f);

    // per-quadrant {sum m, count} + density count (all regions), static indices only
    float v[9];
    #pragma unroll
    for (int k = 0; k < 9; ++k) v[k] = 0.f;
    #pragma unroll
    for (int k = 0; k < 10; ++k) {
        int idx = k * NT + tid;
        int q = idx >> 9;            // region 0..4
        int i = idx & (NB - 1);
        float h = (float)acc[k];
        float hm = h * mc[k];
        v[0] += (q == 0) ? hm : 0.f;  v[4] += (q == 0) ? h : 0.f;
        v[1] += (q == 1) ? hm : 0.f;  v[5] += (q == 1) ? h : 0.f;
        v[2] += (q == 2) ? hm : 0.f;  v[6] += (q == 2) ? h : 0.f;
        v[3] += (q == 3) ? hm : 0.f;  v[7] += (q == 3) ? h : 0.f;
        v[8] += (i > kb) ? h : ((i == kb) ? h * (1.f - frac) : 0.f);
    }
    #pragma unroll
    for (int k = 0; k < 9; ++k) {
        #pragma unroll
        for (int o = 32; o > 0; o >>= 1) v[k] += __shfl_down(v[k], o, 64);
    }
    if (ln == 0) {
        #pragma unroll
        for (int k = 0; k < 9; ++k) shRed[wv][k] = v[k];
    }
    __syncthreads();
    if (tid == 0) {
        float t[9];
        #pragma unroll
        for (int k = 0; k < 9; ++k)
            t[k] = shRed[0][k] + shRed[1][k] + shRed[2][k] + shRed[3][k];
        out[b * 7 + 0] = t[8] * INVN;               // edge_density
        out[b * 7 + 3] = t[0] / (t[4] + 1e-8f);     // angle features
        out[b * 7 + 4] = t[1] / (t[5] + 1e-8f);
        out[b * 7 + 5] = t[2] / (t[6] + 1e-8f);
        out[b * 7 + 6] = t[3] / (t[7] + 1e-8f);
    }
}

extern "C" void kernel_launch(void* const* d_in, const int* in_sizes, int n_in,
                              void* d_out, int out_size, void* d_ws, size_t ws_size,
                              hipStream_t stream) {
    const float* x = (const float*)d_in[0];
    float* out = (float*)d_out;

    unsigned int* hist = (unsigned int*)d_ws;                       // 64*16*2560 u32 ~ 10.5 MB
    unsigned int* maxbits = hist + (size_t)BATCH * STRIPS * NHIST;  // 64 u32

    hipMemsetAsync(maxbits, 0, BATCH * sizeof(unsigned int), stream);

    dim3 grid(STRIPS, BATCH);
    pass1_kernel<<<grid, NT, 0, stream>>>(x, hist, maxbits);
    finalize_kernel<<<BATCH, NT, 0, stream>>>(hist, maxbits, out);
}

// Round 6
// 58.263 us; speedup vs baseline: 1.7084x; 1.3630x over previous
//
#include <hip/hip_runtime.h>

#define BATCH 64
#define H 1024
#define W 1024
#define RPB 64                 // rows per block strip (== wavefront size)
#define STRIPS (H / RPB)       // 16
#define NT 256                 // threads per block (W/4)
#define NB 512                 // log-spaced m^2 bins per region
#define NREG 5                 // quadrants 0..3 + "no-bin" region 4
#define NHIST (NREG * NB)      // 2560
#define BIN_BASE 3776          // (118<<5): lower edge m^2 = 2^-9
#define BIN_SHIFT 18           // keep exponent + 5 mantissa bits
#define INVN (1.0f / (float)(H * W))

// One row of 4 pixels. FIRST = image row 0 (gy forced 0; angle==pi -> region 4).
template<bool FIRST>
__device__ __forceinline__ void do_row(const float4 cur, const float4 pv4, float left,
                                       int col, float& mx2, unsigned int* shHist) {
    float px[4] = {cur.x, cur.y, cur.z, cur.w};
    float pl[4] = {left, cur.x, cur.y, cur.z};
    float pv[4] = {pv4.x, pv4.y, pv4.z, pv4.w};
    #pragma unroll
    for (int j = 0; j < 4; ++j) {
        float gx = px[j] - pl[j];
        if (j == 0) gx = (col == 0) ? 0.f : gx;     // zero-pad of first column
        float gy = FIRST ? 0.0f : (px[j] - pv[j]);
        float m2 = __builtin_fmaf(gx, gx, __builtin_fmaf(gy, gy, 1e-8f));
        mx2 = fmaxf(mx2, m2);
        // quadrant from sign bits of gy and gxp = gx + 1e-8:
        //  (sy,sxp)=(1,1)->q0 [-pi,-pi/2) ; (1,0)->q1 [-pi/2,0)
        //  (0,0)->q2 [0,pi/2)            ; (0,1)->q3 [pi/2,pi)
        //  row 0 (gy==0): gxp>=0 -> angle 0 (q2); gxp<0 -> angle pi -> NO bin (q4)
        unsigned int sxp = __float_as_uint(gx + 1e-8f) >> 31;
        unsigned int q;
        if (FIRST) {
            q = sxp ? 4u : 2u;
        } else {
            unsigned int sy = __float_as_uint(gy) >> 31;
            q = ((sy ^ 1u) << 1) | (sxp ^ sy);
        }
        // log-spaced bin straight from the float bits of m2 (m2 > 0 always)
        int bin = (int)(__float_as_uint(m2) >> BIN_SHIFT) - BIN_BASE;
        bin = bin < 0 ? 0 : (bin > (NB - 1) ? (NB - 1) : bin);
        atomicAdd(&shHist[q * NB + bin], 1u);
    }
}

// ---------------- Pass 1: per-strip 5-region histogram + max(m^2) ----------------
__global__ __launch_bounds__(NT) void pass1_kernel(const float* __restrict__ x,
                                                   unsigned int* __restrict__ hist,
                                                   float* __restrict__ smax) {
    const int strip = blockIdx.x;
    const int b = blockIdx.y;
    const int tid = threadIdx.x;
    const int wave = tid >> 6;
    const int lane = tid & 63;
    const int seg0 = wave << 8;           // wave's 256-col segment base
    const int col = seg0 + (lane << 2);
    const float* img = x + (size_t)b * H * W;
    const int r0 = strip * RPB;
    const int rend = r0 + RPB;

    __shared__ unsigned int shHist[NHIST];
    __shared__ float shMax[4];
    for (int i = tid; i < NHIST; i += NT) shHist[i] = 0u;
    __syncthreads();

    // Preload this wave's left-boundary column: lane l holds img[r0+l][seg0-1].
    // One strided load per strip instead of one scalar load per row in-loop.
    float lb_all = 0.f;
    if (seg0 > 0) lb_all = img[(size_t)(r0 + lane) * W + (seg0 - 1)];

    float mx2 = 0.f;
    float4 prev;
    int r = r0;

    if (r0 == 0) {
        // peel image row 0 (gy==0 path with the no-bin case)
        float4 cur0 = *(const float4*)(img + col);
        float sw = __shfl_up(cur0.w, 1, 64);
        float bb = __shfl(lb_all, 0, 64);
        float left = (lane == 0) ? bb : sw;
        do_row<true>(cur0, cur0, left, col, mx2, shHist);
        prev = cur0;
        r = 1;
    } else {
        prev = *(const float4*)(img + (size_t)(r0 - 1) * W + col);
    }

    // 2-deep row prefetch
    float4 pf0 = *(const float4*)(img + (size_t)r * W + col);
    float4 pf1 = *(const float4*)(img + (size_t)(r + 1) * W + col);  // r+1 < rend always (RPB>=3)

    // odd remaining row count (strip 0 after the peel): do one single row
    if ((rend - r) & 1) {
        float4 c0 = pf0;
        pf0 = pf1;
        if (r + 2 < rend) pf1 = *(const float4*)(img + (size_t)(r + 2) * W + col);
        float sw = __shfl_up(c0.w, 1, 64);
        float bb = __shfl(lb_all, r - r0, 64);
        float left = (lane == 0) ? bb : sw;
        do_row<false>(c0, prev, left, col, mx2, shHist);
        prev = c0;
        ++r;
    }

    // main loop: 2 rows per iteration, prefetch 2 ahead
    for (; r < rend; r += 2) {
        float4 c0 = pf0, c1 = pf1;
        if (r + 3 < rend) {
            pf0 = *(const float4*)(img + (size_t)(r + 2) * W + col);
            pf1 = *(const float4*)(img + (size_t)(r + 3) * W + col);
        }
        float sw0 = __shfl_up(c0.w, 1, 64);
        float bb0 = __shfl(lb_all, r - r0, 64);
        float left0 = (lane == 0) ? bb0 : sw0;
        float sw1 = __shfl_up(c1.w, 1, 64);
        float bb1 = __shfl(lb_all, r + 1 - r0, 64);
        float left1 = (lane == 0) ? bb1 : sw1;
        do_row<false>(c0, prev, left0, col, mx2, shHist);
        do_row<false>(c1, c0, left1, col, mx2, shHist);
        prev = c1;
    }

    // per-strip max(m^2): wave reduce -> cross-wave via LDS -> plain store
    #pragma unroll
    for (int o = 32; o > 0; o >>= 1)
        mx2 = fmaxf(mx2, __shfl_down(mx2, o, 64));
    if (lane == 0) shMax[wave] = mx2;

    __syncthreads();   // all shHist atomics + shMax visible
    if (tid == 0)
        smax[b * STRIPS + strip] =
            fmaxf(fmaxf(shMax[0], shMax[1]), fmaxf(shMax[2], shMax[3]));

    unsigned int* gh = hist + (size_t)(b * STRIPS + strip) * NHIST;
    for (int i = tid; i < NHIST; i += NT) gh[i] = shHist[i];   // coalesced stores
}

// ---------------- Finalize: one block per image, coalesced strip-sum ----------------
__global__ __launch_bounds__(NT) void finalize_kernel(const unsigned int* __restrict__ hist,
                                                      const float* __restrict__ smax,
                                                      float* __restrict__ out) {
    const int b = blockIdx.x;
    const int tid = threadIdx.x;
    const int wv = tid >> 6, ln = tid & 63;
    __shared__ float shRed[4][9];
    __shared__ float shS[4];
    __shared__ float shMean;

    // sum the 16 per-strip histograms; thread owns bins {k*256+tid} (coalesced reads)
    unsigned int acc[10];
    #pragma unroll
    for (int k = 0; k < 10; ++k) acc[k] = 0u;
    const unsigned int* basep = hist + (size_t)b * STRIPS * NHIST;
    for (int s = 0; s < STRIPS; ++s) {
        const unsigned int* src = basep + (size_t)s * NHIST;
        #pragma unroll
        for (int k = 0; k < 10; ++k) acc[k] += src[k * NT + tid];
    }

    // bin centers in m-space: [sqrt(lo)+sqrt(hi)]/2
    float mc[10];
    #pragma unroll
    for (int k = 0; k < 10; ++k) {
        int i = (k * NT + tid) & (NB - 1);
        float lo = __uint_as_float((unsigned int)(i + BIN_BASE) << BIN_SHIFT);
        float hi = __uint_as_float((unsigned int)(i + BIN_BASE + 1) << BIN_SHIFT);
        mc[k] = 0.5f * (sqrtf(lo) + sqrtf(hi));
    }

    // total sum of magnitudes -> mean ; strip-max -> edge_max
    float sv = 0.f;
    #pragma unroll
    for (int k = 0; k < 10; ++k) sv += (float)acc[k] * mc[k];
    #pragma unroll
    for (int o = 32; o > 0; o >>= 1) sv += __shfl_down(sv, o, 64);
    if (ln == 0) shS[wv] = sv;

    float vm = 0.f;
    if (tid < STRIPS) vm = smax[b * STRIPS + tid];
    if (tid < 64) {
        #pragma unroll
        for (int o = 32; o > 0; o >>= 1)
            vm = fmaxf(vm, __shfl_down(vm, o, 64));
    }
    __syncthreads();
    if (tid == 0) {
        float mean = (shS[0] + shS[1] + shS[2] + shS[3]) * INVN;
        shMean = mean;
        out[b * 7 + 1] = mean;          // edge_strength
        out[b * 7 + 2] = sqrtf(vm);     // edge_max (exact)
    }
    __syncthreads();
    const float mean = shMean;

    // density threshold position within its bin (interpolate in m-space)
    float mean2 = mean * mean;
    int kb = (int)(__float_as_uint(mean2) >> BIN_SHIFT) - BIN_BASE;
    kb = kb < 0 ? 0 : (kb > NB - 1 ? NB - 1 : kb);
    float lok = sqrtf(__uint_as_float((unsigned int)(kb + BIN_BASE) << BIN_SHIFT));
    float hik = sqrtf(__uint_as_float((unsigned int)(kb + BIN_BASE + 1) << BIN_SHIFT));
    float frac = (mean - lok) / (hik - lok);
    frac = fminf(fmaxf(frac, 0.f), 1.f);

    // per-quadrant {sum m, count} + density count (all regions), static indices only
    float v[9];
    #pragma unroll
    for (int k = 0; k < 9; ++k) v[k] = 0.f;
    #pragma unroll
    for (int k = 0; k < 10; ++k) {
        int idx = k * NT + tid;
        int q = idx >> 9;            // region 0..4
        int i = idx & (NB - 1);
        float h = (float)acc[k];
        float hm = h * mc[k];
        v[0] += (q == 0) ? hm : 0.f;  v[4] += (q == 0) ? h : 0.f;
        v[1] += (q == 1) ? hm : 0.f;  v[5] += (q == 1) ? h : 0.f;
        v[2] += (q == 2) ? hm : 0.f;  v[6] += (q == 2) ? h : 0.f;
        v[3] += (q == 3) ? hm : 0.f;  v[7] += (q == 3) ? h : 0.f;
        v[8] += (i > kb) ? h : ((i == kb) ? h * (1.f - frac) : 0.f);
    }
    #pragma unroll
    for (int k = 0; k < 9; ++k) {
        #pragma unroll
        for (int o = 32; o > 0; o >>= 1) v[k] += __shfl_down(v[k], o, 64);
    }
    if (ln == 0) {
        #pragma unroll
        for (int k = 0; k < 9; ++k) shRed[wv][k] = v[k];
    }
    __syncthreads();
    if (tid == 0) {
        float t[9];
        #pragma unroll
        for (int k = 0; k < 9; ++k)
            t[k] = shRed[0][k] + shRed[1][k] + shRed[2][k] + shRed[3][k];
        out[b * 7 + 0] = t[8] * INVN;               // edge_density
        out[b * 7 + 3] = t[0] / (t[4] + 1e-8f);     // angle features
        out[b * 7 + 4] = t[1] / (t[5] + 1e-8f);
        out[b * 7 + 5] = t[2] / (t[6] + 1e-8f);
        out[b * 7 + 6] = t[3] / (t[7] + 1e-8f);
    }
}

extern "C" void kernel_launch(void* const* d_in, const int* in_sizes, int n_in,
                              void* d_out, int out_size, void* d_ws, size_t ws_size,
                              hipStream_t stream) {
    const float* x = (const float*)d_in[0];
    float* out = (float*)d_out;

    unsigned int* hist = (unsigned int*)d_ws;                   // 64*16*2560 u32 ~ 10.5 MB
    float* smax = (float*)(hist + (size_t)BATCH * STRIPS * NHIST);  // 64*16 floats

    dim3 grid(STRIPS, BATCH);
    pass1_kernel<<<grid, NT, 0, stream>>>(x, hist, smax);
    finalize_kernel<<<BATCH, NT, 0, stream>>>(hist, smax, out);
}